// Round 1
// baseline (36.701 us; speedup 1.0000x reference)
//
#include <hip/hip_runtime.h>
#include <hip/hip_bf16.h>

#define N_ROWS 4096
#define R_REL  16
#define DIN    256
#define DOUT   256
#define BM     32   // rows per GEMM block

typedef __attribute__((ext_vector_type(4))) float f32x4;
typedef __attribute__((ext_vector_type(8))) short s16x8;

__device__ __forceinline__ short f2bf(float f) {
    union { float f; unsigned u; } v; v.f = f;
    unsigned r = v.u + 0x7FFFu + ((v.u >> 16) & 1u);  // round-to-nearest-even
    return (short)(r >> 16);
}

// ---------------------------------------------------------------------------
// Kernel 1: counting sort of row indices by relation. Single block, 1024 thr.
// Output: offs[17] (exclusive prefix), perm[N] (row ids grouped by relation).
// Bucket-internal order is atomic-arrival-dependent, but out[n] only depends
// on row n's own dot product -> output is deterministic regardless.
// ---------------------------------------------------------------------------
__global__ __launch_bounds__(1024) void sort_rows_kernel(
        const int* __restrict__ rel, int* __restrict__ offs, int* __restrict__ perm) {
    __shared__ int cnt[R_REL];
    __shared__ int cur[R_REL + 1];
    const int t = threadIdx.x;
    if (t < R_REL) cnt[t] = 0;
    __syncthreads();

    int myrel[4];
    #pragma unroll
    for (int i = 0; i < 4; ++i) {
        const int n = t + i * 1024;
        myrel[i] = rel[n];
        atomicAdd(&cnt[myrel[i]], 1);
    }
    __syncthreads();

    if (t == 0) {
        int acc = 0;
        #pragma unroll
        for (int r = 0; r < R_REL; ++r) { cur[r] = acc; acc += cnt[r]; }
        cur[R_REL] = acc;
    }
    __syncthreads();
    if (t <= R_REL) offs[t] = cur[t];
    __syncthreads();   // offs snapshot must complete before cursors mutate

    #pragma unroll
    for (int i = 0; i < 4; ++i) {
        const int n = t + i * 1024;
        const int p = atomicAdd(&cur[myrel[i]], 1);
        perm[p] = n;
    }
}

// ---------------------------------------------------------------------------
// Kernel 2: grouped GEMM. Grid = (ceil(N/BM), R); block (tile,r) computes
// rows perm[offs[r] + tile*BM ... ] x w[r] + bias[r]. Blocks past the bucket
// count exit immediately. 256 threads = 4 waves; wave wv owns cols
// [wv*64, wv*64+64). MFMA 16x16x32 bf16, fp32 accumulate.
// A (gathered x rows) staged once in LDS as bf16; B (w) fragments loaded
// directly global->reg (per-b slice is a coalesced 256B wave read). No
// barriers in the K-loop -> compiler free to pipeline loads under MFMA.
// ---------------------------------------------------------------------------
__global__ __launch_bounds__(256) void rgemm_kernel(
        const float* __restrict__ x, const float* __restrict__ w,
        const float* __restrict__ bias, const int* __restrict__ offs,
        const int* __restrict__ perm, float* __restrict__ out) {
    const int r    = blockIdx.y;
    const int beg  = offs[r];
    const int cnt  = offs[r + 1] - beg;
    const int row0 = blockIdx.x * BM;
    if (row0 >= cnt) return;

    __shared__ int    rowidx[BM];
    __shared__ ushort A[BM][264];   // bf16 bits, row stride 264 (=528B, 16B-aligned, depads banks)

    const int t = threadIdx.x;
    if (t < BM) {
        const int idx = row0 + t;
        rowidx[t] = perm[beg + (idx < cnt ? idx : 0)];  // clamp tail to a valid row
    }
    __syncthreads();

    // Stage A: 32 rows x 256 k, fp32 -> bf16. Thread t: row t/8, 32 cols.
    {
        const int rl = t >> 3;
        const int cg = t & 7;
        const float* src = x + (size_t)rowidx[rl] * DIN + cg * 32;
        s16x8* dst = (s16x8*)&A[rl][cg * 32];
        #pragma unroll
        for (int j = 0; j < 4; ++j) {
            const f32x4 v0 = *(const f32x4*)(src + j * 8);
            const f32x4 v1 = *(const f32x4*)(src + j * 8 + 4);
            s16x8 o;
            o[0] = f2bf(v0[0]); o[1] = f2bf(v0[1]); o[2] = f2bf(v0[2]); o[3] = f2bf(v0[3]);
            o[4] = f2bf(v1[0]); o[5] = f2bf(v1[1]); o[6] = f2bf(v1[2]); o[7] = f2bf(v1[3]);
            dst[j] = o;
        }
    }
    __syncthreads();

    const int lane = t & 63;
    const int wv   = t >> 6;        // wave id 0..3 -> column chunk
    const int frow = lane & 15;     // fragment row/col within 16
    const int kgrp = lane >> 4;     // k-group 0..3 (8 k's each)

    f32x4 acc[2][4] = {};           // [m: 2x16 rows][n: 4x16 cols]

    const float* wbase = w + (size_t)r * DIN * DOUT + wv * 64 + frow;

    #pragma unroll
    for (int ks = 0; ks < DIN / 32; ++ks) {
        // A fragments: lane holds A[m*16+frow][ks*32 + kgrp*8 .. +7]
        s16x8 af[2];
        #pragma unroll
        for (int m = 0; m < 2; ++m)
            af[m] = *(const s16x8*)&A[m * 16 + frow][ks * 32 + kgrp * 8];

        // B fragments from global: lane holds w[k = ks*32+kgrp*8+b][col]
        s16x8 bf[4];
        const float* wk = wbase + (size_t)(ks * 32 + kgrp * 8) * DOUT;
        #pragma unroll
        for (int n = 0; n < 4; ++n) {
            const float* wp = wk + n * 16;
            s16x8 o;
            #pragma unroll
            for (int b = 0; b < 8; ++b) o[b] = f2bf(wp[(size_t)b * DOUT]);
            bf[n] = o;
        }

        #pragma unroll
        for (int m = 0; m < 2; ++m)
            #pragma unroll
            for (int n = 0; n < 4; ++n)
                acc[m][n] = __builtin_amdgcn_mfma_f32_16x16x32_bf16(af[m], bf[n], acc[m][n], 0, 0, 0);
    }

    // Epilogue: D layout col = lane&15, row = (lane>>4)*4 + v  (m89-verified)
    #pragma unroll
    for (int n = 0; n < 4; ++n) {
        const int col = wv * 64 + n * 16 + frow;
        const float bv = bias[r * DOUT + col];
        #pragma unroll
        for (int m = 0; m < 2; ++m) {
            #pragma unroll
            for (int v = 0; v < 4; ++v) {
                const int rl = m * 16 + kgrp * 4 + v;
                if (row0 + rl < cnt)
                    out[(size_t)rowidx[rl] * DOUT + col] = acc[m][n][v] + bv;
            }
        }
    }
}

extern "C" void kernel_launch(void* const* d_in, const int* in_sizes, int n_in,
                              void* d_out, int out_size, void* d_ws, size_t ws_size,
                              hipStream_t stream) {
    const float* x    = (const float*)d_in[0];
    const int*   rel  = (const int*)  d_in[1];
    const float* w    = (const float*)d_in[2];
    const float* bias = (const float*)d_in[3];
    float*       out  = (float*)d_out;

    int* offs = (int*)d_ws;       // 17 ints
    int* perm = offs + 32;        // 4096 ints (128B-aligned)

    sort_rows_kernel<<<1, 1024, 0, stream>>>(rel, offs, perm);

    dim3 grid(N_ROWS / BM, R_REL);   // 128 x 16; blocks past bucket count exit
    rgemm_kernel<<<grid, 256, 0, stream>>>(x, w, bias, offs, perm, out);
}

// Round 2
// 23.151 us; speedup vs baseline: 1.5853x; 1.5853x over previous
//
#include <hip/hip_runtime.h>
#include <hip/hip_bf16.h>

#define N_ROWS 4096
#define R_REL  16
#define DIN    256
#define DOUT   256
#define BM     32

typedef __attribute__((ext_vector_type(4))) float f32x4;
typedef __attribute__((ext_vector_type(8))) short s16x8;
typedef unsigned long long u64;

__device__ __forceinline__ short f2bf(float f) {
    union { float f; unsigned u; } v; v.f = f;
    unsigned r = v.u + 0x7FFFu + ((v.u >> 16) & 1u);  // round-to-nearest-even
    return (short)(r >> 16);
}

// ---------------------------------------------------------------------------
// prep_kernel, grid = 129 blocks x 256 threads:
//   block 0      : ballot-based counting sort of rows by relation
//   blocks 1..64 : w fp32 [R][DIN][DOUT] -> wT bf16 [R][DOUT][DIN] (transposed,
//                  MFMA-B-fragment native: lane reads 8 consecutive k = 16B)
//   blocks 65..128: x fp32 -> bf16 (same layout)
// Sort runs on one CU while conversions run on the others -> overlapped.
// ---------------------------------------------------------------------------
__global__ __launch_bounds__(256) void prep_kernel(
        const float* __restrict__ x, const int* __restrict__ rel,
        const float* __restrict__ w,
        int* __restrict__ offs, int* __restrict__ perm,
        ushort* __restrict__ wT, ushort* __restrict__ xb) {
    const int b = blockIdx.x;
    const int t = threadIdx.x;

    if (b == 0) {
        __shared__ int cnt[R_REL];
        __shared__ int offs_s[R_REL + 1];
        __shared__ int cur[R_REL];
        if (t < R_REL) cnt[t] = 0;
        __syncthreads();

        const int wv = t >> 6, lane = t & 63;
        const u64 ltmask = (1ull << lane) - 1ull;

        int myrel[16];
        #pragma unroll
        for (int it = 0; it < 16; ++it)
            myrel[it] = rel[wv * 1024 + it * 64 + lane];

        // count phase: 4-bit radix ballots -> one atomic per bucket-group
        #pragma unroll
        for (int it = 0; it < 16; ++it) {
            const int v = myrel[it];
            const u64 m0 = __ballot(v & 1), m1 = __ballot(v & 2);
            const u64 m2 = __ballot(v & 4), m3 = __ballot(v & 8);
            const u64 mine = ((v & 1) ? m0 : ~m0) & ((v & 2) ? m1 : ~m1)
                           & ((v & 4) ? m2 : ~m2) & ((v & 8) ? m3 : ~m3);
            const int lead = __ffsll((u64)mine) - 1;
            if (lane == lead) atomicAdd(&cnt[v], __popcll(mine));
        }
        __syncthreads();

        if (t == 0) {
            int a = 0;
            #pragma unroll
            for (int r = 0; r < R_REL; ++r) { offs_s[r] = a; a += cnt[r]; }
            offs_s[R_REL] = a;
        }
        __syncthreads();
        if (t <= R_REL) offs[t] = offs_s[t];
        if (t < R_REL) cur[t] = offs_s[t];
        __syncthreads();

        // scatter phase: leader claims a range, lanes place themselves by rank
        #pragma unroll
        for (int it = 0; it < 16; ++it) {
            const int v = myrel[it];
            const u64 m0 = __ballot(v & 1), m1 = __ballot(v & 2);
            const u64 m2 = __ballot(v & 4), m3 = __ballot(v & 8);
            const u64 mine = ((v & 1) ? m0 : ~m0) & ((v & 2) ? m1 : ~m1)
                           & ((v & 4) ? m2 : ~m2) & ((v & 8) ? m3 : ~m3);
            const int lead = __ffsll((u64)mine) - 1;
            int base = 0;
            if (lane == lead) base = atomicAdd(&cur[v], __popcll(mine));
            base = __shfl(base, lead);
            perm[base + __popcll(mine & ltmask)] = wv * 1024 + it * 64 + lane;
        }
    } else if (b <= 64) {
        // w convert+transpose: block -> (r, kq); thread t = output column.
        // Reads coalesced (lane = consecutive col, 1KB/instr); writes 16B/thread.
        const int r  = (b - 1) >> 2;
        const int kq = (b - 1) & 3;
        const float* src = w + (size_t)r * DIN * DOUT + (size_t)kq * 64 * DOUT + t;
        ushort*      dst = wT + (size_t)r * DIN * DOUT + (size_t)t * DIN + kq * 64;
        #pragma unroll
        for (int p = 0; p < 8; ++p) {
            s16x8 o;
            #pragma unroll
            for (int j = 0; j < 8; ++j)
                o[j] = f2bf(src[(size_t)(p * 8 + j) * DOUT]);
            *(s16x8*)(dst + p * 8) = o;
        }
    } else {
        // x convert: 64 blocks x 256 thr x 64 floats
        const int bb = b - 65;
        #pragma unroll
        for (int j = 0; j < 4; ++j) {
            const size_t base = (size_t)bb * 16384 + (size_t)j * 4096 + (size_t)t * 16;
            const f32x4 v0 = *(const f32x4*)(x + base);
            const f32x4 v1 = *(const f32x4*)(x + base + 4);
            const f32x4 v2 = *(const f32x4*)(x + base + 8);
            const f32x4 v3 = *(const f32x4*)(x + base + 12);
            s16x8 o0, o1;
            o0[0]=f2bf(v0[0]); o0[1]=f2bf(v0[1]); o0[2]=f2bf(v0[2]); o0[3]=f2bf(v0[3]);
            o0[4]=f2bf(v1[0]); o0[5]=f2bf(v1[1]); o0[6]=f2bf(v1[2]); o0[7]=f2bf(v1[3]);
            o1[0]=f2bf(v2[0]); o1[1]=f2bf(v2[1]); o1[2]=f2bf(v2[2]); o1[3]=f2bf(v2[3]);
            o1[4]=f2bf(v3[0]); o1[5]=f2bf(v3[1]); o1[6]=f2bf(v3[2]); o1[7]=f2bf(v3[3]);
            *(s16x8*)(xb + base)     = o0;
            *(s16x8*)(xb + base + 8) = o1;
        }
    }
}

// ---------------------------------------------------------------------------
// Grouped GEMM: grid (32, R, 2). Block (tile, r, c) computes 32 gathered rows
// x 128 cols of out using relation r's weights. grid-stride over tiles for
// safety (practically 1 iteration). 256 thr = 4 waves; wave owns 32 cols.
// A staged once in LDS (bf16, padded rows -> balanced bank quads); B loaded
// straight from fragment-native wT as single 16B loads. No barriers in the
// K-loop -> compiler pipelines loads under MFMA.
// ---------------------------------------------------------------------------
__global__ __launch_bounds__(256) void rgemm_kernel(
        const ushort* __restrict__ xb, const ushort* __restrict__ wT,
        const float* __restrict__ bias, const int* __restrict__ offs,
        const int* __restrict__ perm, float* __restrict__ out) {
    const int r    = blockIdx.y;
    const int beg  = offs[r];
    const int cnt  = offs[r + 1] - beg;
    const int colb = blockIdx.z * 128;
    const int t    = threadIdx.x;
    const int lane = t & 63, wv = t >> 6;
    const int frow = lane & 15, kgrp = lane >> 4;

    __shared__ int    rowidx[BM];
    __shared__ ushort A[BM][264];   // +8 ushort pad: bank quads balanced

    for (int tile = blockIdx.x; tile * BM < cnt; tile += gridDim.x) {
        const int row0 = tile * BM;
        __syncthreads();   // LDS reuse guard across tiles (no-op first iter)
        if (t < BM) {
            const int idx = row0 + t;
            rowidx[t] = perm[beg + (idx < cnt ? idx : cnt - 1)];
        }
        __syncthreads();
        {   // stage A: thread t copies 64B of row t/8
            const int rl = t >> 3, seg = t & 7;
            const ushort* src = xb + (size_t)rowidx[rl] * DIN + seg * 32;
            #pragma unroll
            for (int j = 0; j < 4; ++j)
                *(s16x8*)&A[rl][seg * 32 + j * 8] = *(const s16x8*)(src + j * 8);
        }
        __syncthreads();

        f32x4 acc[2][2] = {};
        const ushort* wb = wT + (size_t)r * DIN * DOUT
                         + (size_t)(colb + wv * 32 + frow) * DIN + kgrp * 8;
        #pragma unroll
        for (int ks = 0; ks < 8; ++ks) {
            const s16x8 af0 = *(const s16x8*)&A[frow][ks * 32 + kgrp * 8];
            const s16x8 af1 = *(const s16x8*)&A[16 + frow][ks * 32 + kgrp * 8];
            const s16x8 bf0 = *(const s16x8*)(wb + ks * 32);
            const s16x8 bf1 = *(const s16x8*)(wb + 16 * DIN + ks * 32);
            acc[0][0] = __builtin_amdgcn_mfma_f32_16x16x32_bf16(af0, bf0, acc[0][0], 0, 0, 0);
            acc[1][0] = __builtin_amdgcn_mfma_f32_16x16x32_bf16(af1, bf0, acc[1][0], 0, 0, 0);
            acc[0][1] = __builtin_amdgcn_mfma_f32_16x16x32_bf16(af0, bf1, acc[0][1], 0, 0, 0);
            acc[1][1] = __builtin_amdgcn_mfma_f32_16x16x32_bf16(af1, bf1, acc[1][1], 0, 0, 0);
        }

        // epilogue: D col = lane&15, row = (lane>>4)*4 + v (m89-verified)
        #pragma unroll
        for (int n = 0; n < 2; ++n) {
            const int col = colb + wv * 32 + n * 16 + frow;
            const float bv = bias[r * DOUT + col];
            #pragma unroll
            for (int m = 0; m < 2; ++m) {
                #pragma unroll
                for (int v = 0; v < 4; ++v) {
                    const int rl = m * 16 + kgrp * 4 + v;
                    if (row0 + rl < cnt)
                        out[(size_t)rowidx[rl] * DOUT + col] = acc[m][n][v] + bv;
                }
            }
        }
    }
}

extern "C" void kernel_launch(void* const* d_in, const int* in_sizes, int n_in,
                              void* d_out, int out_size, void* d_ws, size_t ws_size,
                              hipStream_t stream) {
    const float* x    = (const float*)d_in[0];
    const int*   rel  = (const int*)  d_in[1];
    const float* w    = (const float*)d_in[2];
    const float* bias = (const float*)d_in[3];
    float*       out  = (float*)d_out;

    char* ws = (char*)d_ws;
    int*    offs = (int*)ws;                     // 17 ints
    int*    perm = (int*)(ws + 256);             // 4096 ints
    ushort* wT   = (ushort*)(ws + 0x10000);      // 2 MB bf16, [R][DOUT][DIN]
    ushort* xb   = (ushort*)(ws + 0x210000);     // 2 MB bf16, [N][DIN]

    prep_kernel<<<129, 256, 0, stream>>>(x, rel, w, offs, perm, wT, xb);

    dim3 grid(32, R_REL, 2);
    rgemm_kernel<<<grid, 256, 0, stream>>>(xb, wT, bias, offs, perm, out);
}

// Round 3
// 20.668 us; speedup vs baseline: 1.7758x; 1.1201x over previous
//
#include <hip/hip_runtime.h>
#include <hip/hip_bf16.h>

#define N_ROWS 4096
#define R_REL  16
#define DIN    256
#define DOUT   256
#define BM     32
#define GX     16    // row-tile grid dim (grid-stride covers overflow)

typedef __attribute__((ext_vector_type(4))) float f32x4;
typedef __attribute__((ext_vector_type(8))) short s16x8;
typedef unsigned long long u64;

__device__ __forceinline__ short f2bf(float f) {
    union { float f; unsigned u; } v; v.f = f;
    unsigned r = v.u + 0x7FFFu + ((v.u >> 16) & 1u);  // round-to-nearest-even
    return (short)(r >> 16);
}

// ---------------------------------------------------------------------------
// prep: 144 blocks x 256 thr.
//  blocks 0..127  : (r, ks) w fp32 [R][DIN][DOUT] -> wF bf16 fragment-linear:
//                   wF[((r*8+ks)*256 + col)*32 + kk], k = ks*32 + kk.
//                   Reads lane-coalesced (1KB/instr), writes 64B/thread contig.
//  blocks 128..143: relation r = b-128 compacts matching row ids into
//                   perm[r*4096 + i] (private region -> NO cross-relation
//                   prefix dependency), writes cnt[r]. Bucket-internal order
//                   is arrival-dependent but out[n] depends only on row n's
//                   own dot product -> output deterministic.
// ---------------------------------------------------------------------------
__global__ __launch_bounds__(256) void prep_kernel(
        const float* __restrict__ w, const int* __restrict__ rel,
        ushort* __restrict__ wF, int* __restrict__ perm, int* __restrict__ cnt) {
    const int b = blockIdx.x, t = threadIdx.x;
    if (b < 128) {
        const int r = b >> 3, ks = b & 7;
        const float* src = w + ((size_t)r * DIN + ks * 32) * DOUT + t;
        ushort* dst = wF + (((size_t)r * 8 + ks) * 256 + t) * 32;
        s16x8 o[4];
        #pragma unroll
        for (int q = 0; q < 4; ++q)
            #pragma unroll
            for (int j = 0; j < 8; ++j)
                o[q][j] = f2bf(src[(size_t)(q * 8 + j) * DOUT]);
        #pragma unroll
        for (int q = 0; q < 4; ++q)
            *(s16x8*)(dst + q * 8) = o[q];
    } else {
        const int r = b - 128;
        __shared__ int cur;
        if (t == 0) cur = 0;
        __syncthreads();
        const int lane = t & 63;
        const u64 ltmask = (1ull << lane) - 1ull;
        int* permr = perm + r * N_ROWS;
        #pragma unroll
        for (int it = 0; it < 16; ++it) {
            const int n = it * 256 + t;
            const bool match = (rel[n] == r);
            const u64 m = __ballot(match);
            int wbase = 0;
            if (lane == 0 && m) wbase = atomicAdd(&cur, (int)__popcll(m));
            wbase = __shfl(wbase, 0);
            if (match) permr[wbase + (int)__popcll(m & ltmask)] = n;
        }
        __syncthreads();
        if (t == 0) cnt[r] = cur;
    }
}

// ---------------------------------------------------------------------------
// Grouped GEMM: grid (GX, R, 2). Block (tile, r, ch) computes 32 gathered
// rows x 128 cols. A staged from fp32 x with in-kernel bf16 convert; B loaded
// from fragment-linear wF: each wave B-load is 1KB fully contiguous. Bias
// hoisted above the K-loop. No barriers in K-loop -> compiler pipelines.
// ---------------------------------------------------------------------------
__global__ __launch_bounds__(256) void rgemm_kernel(
        const float* __restrict__ x, const ushort* __restrict__ wF,
        const float* __restrict__ bias, const int* __restrict__ cnt,
        const int* __restrict__ perm, float* __restrict__ out) {
    const int r     = blockIdx.y;
    const int ch    = blockIdx.z;
    const int count = cnt[r];
    const int t     = threadIdx.x;
    const int lane  = t & 63, wv = t >> 6;
    const int frow  = lane & 15, kgrp = lane >> 4;

    __shared__ int    rowidx[BM];
    __shared__ ushort A[BM][264];   // 528B row stride: 2-way banks only (free)

    const int col0 = ch * 128 + wv * 32;
    const float bv0 = bias[r * DOUT + col0 + frow];
    const float bv1 = bias[r * DOUT + col0 + 16 + frow];
    const int*    permr = perm + r * N_ROWS;
    const ushort* wFr   = wF + (size_t)r * 8 * 256 * 32;

    for (int tile = blockIdx.x; tile * BM < count; tile += GX) {
        const int row0 = tile * BM;
        __syncthreads();   // LDS reuse guard (no-op first iter)
        if (t < BM) {
            const int idx = row0 + t;
            rowidx[t] = permr[idx < count ? idx : count - 1];  // clamp tail
        }
        __syncthreads();
        {   // stage A: thread t -> row t/8, 32 floats, fp32->bf16
            const int rl = t >> 3, seg = t & 7;
            const float* src = x + (size_t)rowidx[rl] * DIN + seg * 32;
            #pragma unroll
            for (int q = 0; q < 4; ++q) {
                const f32x4 v0 = *(const f32x4*)(src + q * 8);
                const f32x4 v1 = *(const f32x4*)(src + q * 8 + 4);
                s16x8 o;
                o[0]=f2bf(v0[0]); o[1]=f2bf(v0[1]); o[2]=f2bf(v0[2]); o[3]=f2bf(v0[3]);
                o[4]=f2bf(v1[0]); o[5]=f2bf(v1[1]); o[6]=f2bf(v1[2]); o[7]=f2bf(v1[3]);
                *(s16x8*)&A[rl][seg * 32 + q * 8] = o;
            }
        }
        __syncthreads();

        f32x4 acc[2][2] = {};
        #pragma unroll
        for (int ks = 0; ks < 8; ++ks) {
            const ushort* wb = wFr + (((size_t)ks * 256) + col0 + frow) * 32 + kgrp * 8;
            const s16x8 bf0 = *(const s16x8*)wb;              // wave: 1KB contig
            const s16x8 bf1 = *(const s16x8*)(wb + 16 * 32);  // wave: 1KB contig
            const s16x8 af0 = *(const s16x8*)&A[frow][ks * 32 + kgrp * 8];
            const s16x8 af1 = *(const s16x8*)&A[16 + frow][ks * 32 + kgrp * 8];
            acc[0][0] = __builtin_amdgcn_mfma_f32_16x16x32_bf16(af0, bf0, acc[0][0], 0, 0, 0);
            acc[1][0] = __builtin_amdgcn_mfma_f32_16x16x32_bf16(af1, bf0, acc[1][0], 0, 0, 0);
            acc[0][1] = __builtin_amdgcn_mfma_f32_16x16x32_bf16(af0, bf1, acc[0][1], 0, 0, 0);
            acc[1][1] = __builtin_amdgcn_mfma_f32_16x16x32_bf16(af1, bf1, acc[1][1], 0, 0, 0);
        }

        // epilogue: D col = lane&15, row = (lane>>4)*4 + v (m89-verified)
        #pragma unroll
        for (int n = 0; n < 2; ++n) {
            const int col = col0 + n * 16 + frow;
            const float bv = n ? bv1 : bv0;
            #pragma unroll
            for (int m = 0; m < 2; ++m) {
                #pragma unroll
                for (int v = 0; v < 4; ++v) {
                    const int rl = m * 16 + kgrp * 4 + v;
                    if (row0 + rl < count)
                        out[(size_t)rowidx[rl] * DOUT + col] = acc[m][n][v] + bv;
                }
            }
        }
    }
}

extern "C" void kernel_launch(void* const* d_in, const int* in_sizes, int n_in,
                              void* d_out, int out_size, void* d_ws, size_t ws_size,
                              hipStream_t stream) {
    const float* x    = (const float*)d_in[0];
    const int*   rel  = (const int*)  d_in[1];
    const float* w    = (const float*)d_in[2];
    const float* bias = (const float*)d_in[3];
    float*       out  = (float*)d_out;

    char* ws = (char*)d_ws;
    int*    cnt  = (int*)ws;                 // 16 ints
    int*    perm = (int*)(ws + 0x100);       // 16*4096 ints = 256KB
    ushort* wF   = (ushort*)(ws + 0x50000);  // 2MB bf16 fragment-linear

    prep_kernel<<<144, 256, 0, stream>>>(w, rel, wF, perm, cnt);

    dim3 grid(GX, R_REL, 2);
    rgemm_kernel<<<grid, 256, 0, stream>>>(x, wF, bias, cnt, perm, out);
}

// Round 4
// 17.930 us; speedup vs baseline: 2.0469x; 1.1527x over previous
//
#include <hip/hip_runtime.h>

#define R_REL 16
#define DIN   256
#define DOUT  256
#define BM    32
#define GX    16
#define CHUNK 128

typedef __attribute__((ext_vector_type(4))) float f32x4;
typedef __attribute__((ext_vector_type(8))) short s16x8;
typedef unsigned long long u64;

__device__ __forceinline__ short f2bf(float f) {
    union { float f; unsigned u; } v; v.f = f;
    unsigned r = v.u + 0x7FFFu + ((v.u >> 16) & 1u);  // round-to-nearest-even
    return (short)(r >> 16);
}

#define MFMA(a, b, c) __builtin_amdgcn_mfma_f32_16x16x32_bf16(a, b, c, 0, 0, 0)

// ---------------------------------------------------------------------------
// Single fused kernel. Block (tile, r, ch): 32 rows of relation r x 128 cols.
//  1) self-sort: 2-pass ballot compaction of rel[] -> own rowidx (no prep
//     kernel, no inter-block dependency; bucket order = ascending row id,
//     fully deterministic).
//  2) A: gathered x rows, fp32->bf16, LDS [32][264] (row-fragment layout).
//  3) B: per K-step, w fp32 read coalesced (wave = 64 consecutive cols,
//     256B/instr), f2bf, transposed store into col-major LDS Bc[128][40]
//     (stride 40 ushort = 80B: write b128 & read b128 both evenly spread
//     across bank groups -> at LDS floor). Double-buffered, 1 barrier/K-step;
//     next-step global loads issued before the barrier to overlap MFMA.
//  4) epilogue: bias add + guarded scatter (m89-verified D layout).
// ---------------------------------------------------------------------------
__global__ __launch_bounds__(256) void fused_kernel(
        const float* __restrict__ x, const int* __restrict__ rel,
        const float* __restrict__ w, const float* __restrict__ bias,
        float* __restrict__ out) {
    const int r    = blockIdx.y;
    const int ch   = blockIdx.z;
    const int t    = threadIdx.x;
    const int lane = t & 63, wv = t >> 6;
    const int frow = lane & 15, kgrp = lane >> 4;

    __shared__ int    wcnt[65];          // 64 per-(wave,it) counts -> excl prefix; [64]=count
    __shared__ int    rowidx[BM];
    __shared__ ushort A[BM][264];        // 528B row stride, b128-aligned
    __shared__ ushort Bc[2][CHUNK][40];  // col-major bf16 B, double-buffered

    // ---- self-sort pass 1: counts + exclusive prefix (row order = n asc) ----
    int myrel[16];
    #pragma unroll
    for (int it = 0; it < 16; ++it)
        myrel[it] = rel[wv * 1024 + it * 64 + lane];

    #pragma unroll
    for (int it = 0; it < 16; ++it) {
        const u64 m = __ballot(myrel[it] == r);
        if (lane == 0) wcnt[wv * 16 + it] = (int)__popcll(m);
    }
    __syncthreads();
    if (wv == 0) {                       // 64-entry exclusive scan by wave 0
        int c = wcnt[lane];
        const int orig = c;
        #pragma unroll
        for (int d = 1; d < 64; d <<= 1) {
            const int u = __shfl_up(c, d);
            if (lane >= d) c += u;
        }
        wcnt[lane] = c - orig;
        if (lane == 63) wcnt[64] = c;    // total count for relation r
    }
    __syncthreads();
    const int count = wcnt[64];

    const int col0 = ch * CHUNK;
    const int colw = col0 + wv * 32;
    const float bv0 = bias[r * DOUT + colw + frow];
    const float bv1 = bias[r * DOUT + colw + 16 + frow];

    const u64 ltmask = (1ull << lane) - 1ull;
    const int half  = t >> 7;            // 0/1: which 16-k half this thread stages
    const int colr  = t & 127;           // staging column
    const float* wcol = w + (size_t)r * DIN * DOUT + col0 + colr;

    for (int tile = blockIdx.x; tile * BM < count; tile += GX) {
        const int row0 = tile * BM;
        __syncthreads();                 // LDS reuse guard (A/Bc/rowidx readers done)

        // ---- pass 2: scatter this tile's row ids (disjoint with tail init) ----
        if (t < BM && row0 + t >= count) rowidx[t] = 0;   // tail fallback (masked later)
        #pragma unroll
        for (int it = 0; it < 16; ++it) {
            const bool match = (myrel[it] == r);
            const u64 m = __ballot(match);
            if (match) {
                const int rank = wcnt[wv * 16 + it] + (int)__popcll(m & ltmask);
                const int s = rank - row0;
                if (s >= 0 && s < BM) rowidx[s] = wv * 1024 + it * 64 + lane;
            }
        }
        __syncthreads();

        // ---- stage A: thread -> row t/8, 32 floats, fp32->bf16 ----
        {
            const int rl = t >> 3, seg = t & 7;
            const float* src = x + (size_t)rowidx[rl] * DIN + seg * 32;
            #pragma unroll
            for (int q = 0; q < 4; ++q) {
                const f32x4 v0 = *(const f32x4*)(src + q * 8);
                const f32x4 v1 = *(const f32x4*)(src + q * 8 + 4);
                s16x8 o;
                o[0]=f2bf(v0[0]); o[1]=f2bf(v0[1]); o[2]=f2bf(v0[2]); o[3]=f2bf(v0[3]);
                o[4]=f2bf(v1[0]); o[5]=f2bf(v1[1]); o[6]=f2bf(v1[2]); o[7]=f2bf(v1[3]);
                *(s16x8*)&A[rl][seg * 32 + q * 8] = o;
            }
        }

        // ---- K pipeline: double-buffered B transpose + MFMA ----
        float g[16];
        #pragma unroll
        for (int i = 0; i < 16; ++i)     // preload ks=0
            g[i] = wcol[(size_t)(half * 16 + i) * DOUT];

        f32x4 acc[2][2] = {};
        #pragma unroll
        for (int ks = 0; ks < 8; ++ks) {
            s16x8 o0, o1;
            #pragma unroll
            for (int i = 0; i < 8; ++i) { o0[i] = f2bf(g[i]); o1[i] = f2bf(g[8 + i]); }
            {
                ushort* dst = &Bc[ks & 1][colr][half * 16];
                *(s16x8*)dst       = o0;
                *(s16x8*)(dst + 8) = o1;
            }
            float gn[16];
            if (ks < 7) {                // issue next-step loads before barrier
                #pragma unroll
                for (int i = 0; i < 16; ++i)
                    gn[i] = wcol[(size_t)((ks + 1) * 32 + half * 16 + i) * DOUT];
            }
            __syncthreads();             // Bc[ks&1] writes visible (covers A at ks=0)

            const s16x8 af0 = *(const s16x8*)&A[frow][ks * 32 + kgrp * 8];
            const s16x8 af1 = *(const s16x8*)&A[16 + frow][ks * 32 + kgrp * 8];
            const s16x8 bf0 = *(const s16x8*)&Bc[ks & 1][wv * 32 + frow][kgrp * 8];
            const s16x8 bf1 = *(const s16x8*)&Bc[ks & 1][wv * 32 + 16 + frow][kgrp * 8];
            acc[0][0] = MFMA(af0, bf0, acc[0][0]);
            acc[1][0] = MFMA(af1, bf0, acc[1][0]);
            acc[0][1] = MFMA(af0, bf1, acc[0][1]);
            acc[1][1] = MFMA(af1, bf1, acc[1][1]);

            if (ks < 7) {
                #pragma unroll
                for (int i = 0; i < 16; ++i) g[i] = gn[i];
            }
        }

        // ---- epilogue: D col = lane&15, row = (lane>>4)*4 + v (m89-verified) ----
        #pragma unroll
        for (int n = 0; n < 2; ++n) {
            const int col = colw + n * 16 + frow;
            const float bv = n ? bv1 : bv0;
            #pragma unroll
            for (int m = 0; m < 2; ++m) {
                #pragma unroll
                for (int v = 0; v < 4; ++v) {
                    const int rl = m * 16 + kgrp * 4 + v;
                    if (row0 + rl < count)
                        out[(size_t)rowidx[rl] * DOUT + col] = acc[m][n][v] + bv;
                }
            }
        }
    }
}

extern "C" void kernel_launch(void* const* d_in, const int* in_sizes, int n_in,
                              void* d_out, int out_size, void* d_ws, size_t ws_size,
                              hipStream_t stream) {
    const float* x    = (const float*)d_in[0];
    const int*   rel  = (const int*)  d_in[1];
    const float* w    = (const float*)d_in[2];
    const float* bias = (const float*)d_in[3];
    float*       out  = (float*)d_out;

    dim3 grid(GX, R_REL, 2);   // 512 blocks, ~256 MFMA-active, self-sufficient
    fused_kernel<<<grid, 256, 0, stream>>>(x, rel, w, bias, out);
}

// Round 5
// 16.946 us; speedup vs baseline: 2.1658x; 1.0581x over previous
//
#include <hip/hip_runtime.h>

#define R_REL 16
#define DIN   256
#define DOUT  256
#define BM    32
#define GX    12
#define CHUNK 64
#define NCH   (DOUT / CHUNK)   // 4

typedef __attribute__((ext_vector_type(4))) float f32x4;
typedef __attribute__((ext_vector_type(4))) int   i32x4;
typedef __attribute__((ext_vector_type(8))) short s16x8;
typedef unsigned long long u64;

#define MFMA(a, b, c) __builtin_amdgcn_mfma_f32_16x16x32_bf16(a, b, c, 0, 0, 0)

__device__ __forceinline__ short f2bf(float f) {
    union { float f; unsigned u; } v; v.f = f;
    unsigned r = v.u + 0x7FFFu + ((v.u >> 16) & 1u);  // round-to-nearest-even
    return (short)(r >> 16);
}

// T2 XOR swizzle (guide §6 G4): tile-row rc (A-row / B-col), element k.
// 16B-granule swizzle keeps b128 alignment; K-loop reads are bank-balanced.
__device__ __forceinline__ int swz(int rc, int k) {
    return rc * 256 + (k ^ ((rc & 7) << 3));
}

// ---------------------------------------------------------------------------
// One fused kernel, 4 barriers per active block, no barriers in MFMA loop.
// Block (tile, r, ch): 32 sorted rows of relation r x 64 cols [ch*64, +64).
//   phase 0: rel via 4x int4; ballot histogram; wave-0 scan  (idle blocks exit)
//   phase 1: issue ALL B loads (64 fp32/thread); ballot-scatter rowidx
//   phase 2: issue A gathers; convert B (VALU hides A latency); convert A;
//            both stored to XOR-swizzled LDS; one barrier
//   phase 3: 8 K-steps of {3 ds_read_b128 + 2 MFMA}, barrier-free
//   phase 4: bias + guarded scatter store (m89-verified D layout)
// ---------------------------------------------------------------------------
__global__ __launch_bounds__(256) void fused_kernel(
        const float* __restrict__ x, const int* __restrict__ rel,
        const float* __restrict__ w, const float* __restrict__ bias,
        float* __restrict__ out) {
    const int r    = blockIdx.y;
    const int ch   = blockIdx.z;
    const int t    = threadIdx.x;
    const int lane = t & 63, wv = t >> 6;
    const int frow = lane & 15, kgrp = lane >> 4;

    __shared__ int    wcnt[65];          // per-(wave,it) exclusive prefix; [64]=count
    __shared__ int    rowidx[BM];
    __shared__ ushort A [BM * 256];      // swizzled bf16 A tile   (16 KB)
    __shared__ ushort Bc[CHUNK * 256];   // swizzled col-major B   (32 KB)

    // ---- phase 0: sort pass 1 ----
    i32x4 mr[4];                         // rel[t*16 .. t*16+15]
    {
        const i32x4* rp = (const i32x4*)(rel + t * 16);
        #pragma unroll
        for (int i = 0; i < 4; ++i) mr[i] = rp[i];
    }
    #pragma unroll
    for (int i = 0; i < 4; ++i)
        #pragma unroll
        for (int j = 0; j < 4; ++j) {
            const u64 m = __ballot(mr[i][j] == r);
            if (lane == 0) wcnt[wv * 16 + i * 4 + j] = (int)__popcll(m);
        }
    __syncthreads();
    if (wv == 0) {                       // 64-entry exclusive scan
        int c = wcnt[lane];
        const int orig = c;
        #pragma unroll
        for (int d = 1; d < 64; d <<= 1) {
            const int u_ = __shfl_up(c, d);
            if (lane >= d) c += u_;
        }
        wcnt[lane] = c - orig;
        if (lane == 63) wcnt[64] = c;
    }
    __syncthreads();
    const int count = wcnt[64];
    if (blockIdx.x * BM >= count) return;   // idle block: no w/x traffic at all

    // ---- phase 1: front-issue the whole B chunk ----
    const int col0 = ch * CHUNK;
    const int c4   = (t & 15) * 4;          // local col base
    const int kb   = (t >> 4) * 16;         // k base
    const float* wp = w + ((size_t)r * DIN + kb) * DOUT + col0 + c4;
    f32x4 g[16];
    #pragma unroll
    for (int i = 0; i < 16; ++i)
        g[i] = *(const f32x4*)(wp + (size_t)i * DOUT);

    const u64 ltmask = (1ull << lane) - 1ull;
    const int colg = col0 + wv * 16 + frow;      // this thread's output column
    const float bv = bias[r * DOUT + colg];

    bool first = true;
    for (int tile = blockIdx.x; tile * BM < count; tile += GX) {
        const int row0 = tile * BM;
        if (!first) __syncthreads();             // LDS reuse guard (iter >= 2)

        // scatter this tile's row ids (prefill tail slots; disjoint writes)
        if (t < BM && row0 + t >= count) rowidx[t] = 0;
        #pragma unroll
        for (int i = 0; i < 4; ++i)
            #pragma unroll
            for (int j = 0; j < 4; ++j) {
                const bool match = (mr[i][j] == r);
                const u64 m = __ballot(match);
                if (match) {
                    const int s = wcnt[wv * 16 + i * 4 + j]
                                + (int)__popcll(m & ltmask) - row0;
                    if (s >= 0 && s < BM) rowidx[s] = t * 16 + i * 4 + j;
                }
            }
        __syncthreads();

        // ---- phase 2: A gather issue, then B/A convert+stage ----
        const int arow = t >> 3, aseg = t & 7;
        const float* ax = x + (size_t)rowidx[arow] * DIN + aseg * 32;
        f32x4 av[8];
        #pragma unroll
        for (int q = 0; q < 8; ++q) av[q] = *(const f32x4*)(ax + q * 4);

        if (first) {                             // B staged once per block
            first = false;
            #pragma unroll
            for (int j = 0; j < 4; ++j) {
                s16x8 o0, o1;
                #pragma unroll
                for (int i = 0; i < 8; ++i) {
                    o0[i] = f2bf(g[i][j]);
                    o1[i] = f2bf(g[8 + i][j]);
                }
                const int c = c4 + j;
                *(s16x8*)&Bc[swz(c, kb)]     = o0;
                *(s16x8*)&Bc[swz(c, kb + 8)] = o1;
            }
        }
        #pragma unroll
        for (int q = 0; q < 4; ++q) {            // A: 8 k-consecutive bf16 / store
            s16x8 o;
            #pragma unroll
            for (int j = 0; j < 4; ++j) {
                o[j]     = f2bf(av[2 * q][j]);
                o[4 + j] = f2bf(av[2 * q + 1][j]);
            }
            *(s16x8*)&A[swz(arow, aseg * 32 + q * 8)] = o;
        }
        __syncthreads();

        // ---- phase 3: barrier-free MFMA loop ----
        f32x4 acc0 = {}, acc1 = {};
        #pragma unroll
        for (int ks = 0; ks < 8; ++ks) {
            const int ke = ks * 32 + kgrp * 8;
            const s16x8 af0 = *(const s16x8*)&A[swz(frow, ke)];
            const s16x8 af1 = *(const s16x8*)&A[swz(frow + 16, ke)];
            const s16x8 bf  = *(const s16x8*)&Bc[swz(wv * 16 + frow, ke)];
            acc0 = MFMA(af0, bf, acc0);
            acc1 = MFMA(af1, bf, acc1);
        }

        // ---- phase 4: epilogue (D: col = lane&15, row = (lane>>4)*4+v) ----
        #pragma unroll
        for (int m = 0; m < 2; ++m)
            #pragma unroll
            for (int v = 0; v < 4; ++v) {
                const int s = m * 16 + kgrp * 4 + v;
                if (row0 + s < count)
                    out[(size_t)rowidx[s] * DOUT + colg] =
                        (m ? acc1[v] : acc0[v]) + bv;
            }
    }
}

extern "C" void kernel_launch(void* const* d_in, const int* in_sizes, int n_in,
                              void* d_out, int out_size, void* d_ws, size_t ws_size,
                              hipStream_t stream) {
    const float* x    = (const float*)d_in[0];
    const int*   rel  = (const int*)  d_in[1];
    const float* w    = (const float*)d_in[2];
    const float* bias = (const float*)d_in[3];
    float*       out  = (float*)d_out;

    dim3 grid(GX, R_REL, NCH);   // 768 blocks ≈ 3/CU; grid-stride covers any skew
    fused_kernel<<<grid, 256, 0, stream>>>(x, rel, w, bias, out);
}

// Round 6
// 16.614 us; speedup vs baseline: 2.2091x; 1.0200x over previous
//
#include <hip/hip_runtime.h>
#include <hip/hip_bf16.h>

#define R_REL 16
#define DIN   256
#define DOUT  256
#define BM    32
#define GX    10
#define CHUNK 64
#define NCH   (DOUT / CHUNK)   // 4

typedef __attribute__((ext_vector_type(4))) float f32x4;
typedef __attribute__((ext_vector_type(4))) int   i32x4;
typedef __attribute__((ext_vector_type(8))) short s16x8;
typedef unsigned long long u64;

#define MFMA(a, b, c) __builtin_amdgcn_mfma_f32_16x16x32_bf16(a, b, c, 0, 0, 0)

// Compiler-native f32->bf16 (RNE). m240: scalar casts get good codegen
// (v_cvt-based), ~3x cheaper than the manual 3-op bit-twiddle RNE.
__device__ __forceinline__ short f2bf(float f) {
    union { __hip_bfloat16 h; ushort u; } v;
    v.h = __float2bfloat16(f);
    return (short)v.u;
}

// T2 XOR swizzle: tile-row rc, element k; 8-elem (16B) granule keeps b128
// alignment, spreads the k-stride across bank groups.
__device__ __forceinline__ int swz(int rc, int k) {
    return rc * 256 + (k ^ ((rc & 7) << 3));
}

// ---------------------------------------------------------------------------
// One fused kernel, 3 barriers per active block.
// Block (tile, r, ch): 32 sorted rows of relation r x 64 cols.
//   issue rel + w + bias loads back-to-back (w/bias independent of the sort,
//     issued BEFORE any branch so they fly under the ballot/scan phase)
//   ballot histogram -> barrier -> ALL-wave redundant 64-entry shfl scan
//     (no wave-0 serialization, no second barrier); idle blocks exit
//   ballot-scatter rowidx -> barrier -> A gather issue; B+A convert to
//     swizzled LDS -> barrier -> 8 barrier-free K-steps -> epilogue
// ---------------------------------------------------------------------------
__global__ __launch_bounds__(256) void fused_kernel(
        const float* __restrict__ x, const int* __restrict__ rel,
        const float* __restrict__ w, const float* __restrict__ bias,
        float* __restrict__ out) {
    const int r    = blockIdx.y;
    const int ch   = blockIdx.z;
    const int t    = threadIdx.x;
    const int lane = t & 63, wv = t >> 6;
    const int frow = lane & 15, kgrp = lane >> 4;

    __shared__ int    wcnt[64];
    __shared__ int    rowidx[BM];
    __shared__ ushort A [BM * 256];      // swizzled bf16 A   (16 KB)
    __shared__ ushort Bc[CHUNK * 256];   // swizzled bf16 B^T (32 KB)

    // ---- issue everything independent, up front ----
    i32x4 mr[4];                         // rel[t*16 .. +15]
    {
        const i32x4* rp = (const i32x4*)(rel + t * 16);
        #pragma unroll
        for (int i = 0; i < 4; ++i) mr[i] = rp[i];
    }
    const int col0 = ch * CHUNK;
    const int c4   = (t & 15) * 4;
    const int kb   = (t >> 4) * 16;
    const float* wp = w + ((size_t)r * DIN + kb) * DOUT + col0 + c4;
    f32x4 g[16];
    #pragma unroll
    for (int i = 0; i < 16; ++i)
        g[i] = *(const f32x4*)(wp + (size_t)i * DOUT);

    const int colg = col0 + wv * 16 + frow;
    const float bv = bias[r * DOUT + colg];

    // ---- histogram (waits only on mr) ----
    #pragma unroll
    for (int i = 0; i < 4; ++i)
        #pragma unroll
        for (int j = 0; j < 4; ++j) {
            const u64 m = __ballot(mr[i][j] == r);
            if (lane == 0) wcnt[wv * 16 + i * 4 + j] = (int)__popcll(m);
        }
    __syncthreads();

    // ---- all-wave redundant exclusive scan of the 64 entries ----
    int e, count;
    {
        int c = wcnt[lane];
        const int orig = c;
        #pragma unroll
        for (int d = 1; d < 64; d <<= 1) {
            const int u_ = __shfl_up(c, d);
            if (lane >= d) c += u_;
        }
        count = __shfl(c, 63);
        e = c - orig;                    // exclusive prefix of entry `lane`
    }
    if (blockIdx.x * BM >= count) return;

    const u64 ltmask = (1ull << lane) - 1ull;
    bool first = true;

    for (int tile = blockIdx.x; tile * BM < count; tile += GX) {
        const int row0 = tile * BM;
        if (!first) __syncthreads();     // LDS reuse guard (never taken in practice)

        // ---- scatter this tile's row ids (disjoint with tail init) ----
        if (t < BM && row0 + t >= count) rowidx[t] = 0;
        #pragma unroll
        for (int i = 0; i < 4; ++i)
            #pragma unroll
            for (int j = 0; j < 4; ++j) {
                const int idx = wv * 16 + i * 4 + j;
                const int pfx = __shfl(e, idx);          // entry's bucket prefix
                const bool match = (mr[i][j] == r);
                const u64 m = __ballot(match);
                if (match) {
                    const int s = pfx + (int)__popcll(m & ltmask) - row0;
                    if (s >= 0 && s < BM) rowidx[s] = t * 16 + i * 4 + j;
                }
            }
        __syncthreads();

        // ---- A gather issue, then B (once) / A convert + stage ----
        const int arow = t >> 3, aseg = t & 7;
        const float* ax = x + (size_t)rowidx[arow] * DIN + aseg * 32;
        f32x4 av[8];
        #pragma unroll
        for (int q = 0; q < 8; ++q) av[q] = *(const f32x4*)(ax + q * 4);

        if (first) {
            first = false;
            #pragma unroll
            for (int j = 0; j < 4; ++j) {
                s16x8 o0, o1;
                #pragma unroll
                for (int i = 0; i < 8; ++i) {
                    o0[i] = f2bf(g[i][j]);
                    o1[i] = f2bf(g[8 + i][j]);
                }
                const int c = c4 + j;
                *(s16x8*)&Bc[swz(c, kb)]     = o0;
                *(s16x8*)&Bc[swz(c, kb + 8)] = o1;
            }
        }
        #pragma unroll
        for (int q = 0; q < 4; ++q) {
            s16x8 o;
            #pragma unroll
            for (int j = 0; j < 4; ++j) {
                o[j]     = f2bf(av[2 * q][j]);
                o[4 + j] = f2bf(av[2 * q + 1][j]);
            }
            *(s16x8*)&A[swz(arow, aseg * 32 + q * 8)] = o;
        }
        __syncthreads();

        // ---- barrier-free MFMA loop ----
        f32x4 acc0 = {}, acc1 = {};
        #pragma unroll
        for (int ks = 0; ks < 8; ++ks) {
            const int ke = ks * 32 + kgrp * 8;
            const s16x8 af0 = *(const s16x8*)&A[swz(frow, ke)];
            const s16x8 af1 = *(const s16x8*)&A[swz(frow + 16, ke)];
            const s16x8 bf  = *(const s16x8*)&Bc[swz(wv * 16 + frow, ke)];
            acc0 = MFMA(af0, bf, acc0);
            acc1 = MFMA(af1, bf, acc1);
        }

        // ---- epilogue (D: col = lane&15, row = (lane>>4)*4+v, m89) ----
        #pragma unroll
        for (int m = 0; m < 2; ++m)
            #pragma unroll
            for (int v = 0; v < 4; ++v) {
                const int s = m * 16 + kgrp * 4 + v;
                if (row0 + s < count)
                    out[(size_t)rowidx[s] * DOUT + colg] =
                        (m ? acc1[v] : acc0[v]) + bv;
            }
    }
}

extern "C" void kernel_launch(void* const* d_in, const int* in_sizes, int n_in,
                              void* d_out, int out_size, void* d_ws, size_t ws_size,
                              hipStream_t stream) {
    const float* x    = (const float*)d_in[0];
    const int*   rel  = (const int*)  d_in[1];
    const float* w    = (const float*)d_in[2];
    const float* bias = (const float*)d_in[3];
    float*       out  = (float*)d_out;

    dim3 grid(GX, R_REL, NCH);   // 640 blocks; grid-stride covers any count skew
    fused_kernel<<<grid, 256, 0, stream>>>(x, rel, w, bias, out);
}